// Round 6
// baseline (4023.890 us; speedup 1.0000x reference)
//
#include <hip/hip_runtime.h>
#include <type_traits>

constexpr int NN = 5000;   // nodes
constexpr int NP = 5120;   // padded nodes / K
constexpr int TT = 12;     // enc/dec length
constexpr int UU = 32;     // rnn units
constexpr int FP = 48;     // padded feature rows
constexpr int FR = 33;     // real feature rows (IN+U)
constexpr int DN = 99;     // DIN
constexpr int KC = 128;    // K chunk (fragment layout)
constexpr int NKC = NP / KC;                 // 40
constexpr int CHE = FP * KC;                 // 6144 elems per chunk

typedef __attribute__((ext_vector_type(8))) short short8;
typedef __attribute__((ext_vector_type(4))) float f32x4;

__device__ __forceinline__ unsigned short f2bf(float x) {
  union { float f; unsigned u; } c; c.f = x;
  return (unsigned short)((c.u + 0x7FFFu + ((c.u >> 16) & 1u)) >> 16);
}

// MFMA A-operand fragment layout for X^T: element (f, k) placed so a wave's
// 16B load at base+lane*16 is coalesced; lane&15 = f&15 (D-row), lane>>4 = K-octet.
__device__ __forceinline__ int flatXF(int f, int node) {
  int chunk = node >> 7;
  int ks = (node >> 5) & 3;
  int q = (node >> 3) & 3;
  int j = node & 7;
  int t3 = f >> 4;
  int m = f & 15;
  return chunk * CHE + t3 * 2048 + ks * 512 + (m + 16 * q) * 8 + j;
}

__global__ void k_zero(uint4* __restrict__ p, int n) {
  int i = blockIdx.x * 256 + threadIdx.x;
  if (i < n) p[i] = make_uint4(0u, 0u, 0u, 0u);
}

__global__ void k_initx0(const float* __restrict__ in, float* __restrict__ xf,
                         unsigned short* __restrict__ xb) {
  int n = blockIdx.x * 256 + threadIdx.x;
  if (n >= NP) return;
  float v = (n < NN) ? in[(size_t)n * TT] : 0.f;
  xf[n] = v;
  xb[flatXF(0, n)] = f2bf(v);
}

// ---------------- fused path kernels ----------------

// cast adj(f32, NN x NN) -> adjb(bf16, NP x NP, zero-padded) AND adjT = adjb^T
__global__ __launch_bounds__(256) void k_castT(const float* __restrict__ adj,
                                               unsigned short* __restrict__ adjb,
                                               unsigned short* __restrict__ adjT) {
  __shared__ unsigned short T[64][72];
  const int i0 = blockIdx.y * 64, j0 = blockIdx.x * 64;
  const int tid = threadIdx.x;
  const int r = tid >> 2, cq = tid & 3;
  {
    int i = i0 + r, jb = j0 + cq * 16;
    union { uint4 u[2]; unsigned short s[16]; } pk;
    if (i < NN && jb + 16 <= NN) {
      const float* src = adj + (size_t)i * NN + jb;
#pragma unroll
      for (int k = 0; k < 16; k += 4) {
        float4 v = *(const float4*)(src + k);
        pk.s[k] = f2bf(v.x); pk.s[k + 1] = f2bf(v.y);
        pk.s[k + 2] = f2bf(v.z); pk.s[k + 3] = f2bf(v.w);
      }
    } else {
      for (int k = 0; k < 16; ++k) {
        int j = jb + k;
        pk.s[k] = (i < NN && j < NN) ? f2bf(adj[(size_t)i * NN + j]) : (unsigned short)0;
      }
    }
    *(uint4*)(adjb + (size_t)i * NP + jb) = pk.u[0];
    *(uint4*)(adjb + (size_t)i * NP + jb + 8) = pk.u[1];
    *(uint4*)(&T[r][cq * 16]) = pk.u[0];
    *(uint4*)(&T[r][cq * 16 + 8]) = pk.u[1];
  }
  __syncthreads();
  {
    int jr = tid >> 2, ciq = tid & 3;
    int jo = j0 + jr, ib = i0 + ciq * 16;
    union { uint4 u[2]; unsigned short s[16]; } pk;
#pragma unroll
    for (int k = 0; k < 16; ++k) pk.s[k] = T[ciq * 16 + k][jr];
    *(uint4*)(adjT + (size_t)jo * NP + ib) = pk.u[0];
    *(uint4*)(adjT + (size_t)jo * NP + ib + 8) = pk.u[1];
  }
}

// A2 = A @ A (bf16 in, f32 acc, bf16 out). C[i][k'] = sum_j A[i][j]*AT[k'][j].
// 128x128 tile per block, 512 thr = 8 waves; wave w: rows i0+w*16..+16, all 128 k'.
__global__ __launch_bounds__(512, 4) void k_sq(const unsigned short* __restrict__ adjb,
                                               const unsigned short* __restrict__ adjT,
                                               unsigned short* __restrict__ adj2b) {
  const int tid = threadIdx.x;
  const int w = tid >> 6;
  const int lane = tid & 63;
  const int m = lane & 15;
  const int q = lane >> 4;
  const int i0 = blockIdx.y * 128, k0 = blockIdx.x * 128;

  const unsigned short* aRow = adjb + (size_t)(i0 + w * 16 + m) * NP + q * 8;
  const unsigned short* bT = adjT + (size_t)(k0 + m) * NP + q * 8;

  f32x4 acc[8] = {};
#pragma unroll 2
  for (int j = 0; j < NP; j += 32) {
    short8 av = *(const short8*)(aRow + j);
#pragma unroll
    for (int s = 0; s < 8; ++s) {
      short8 bv = *(const short8*)(bT + (size_t)s * 16 * NP + j);
      acc[s] = __builtin_amdgcn_mfma_f32_16x16x32_bf16(av, bv, acc[s], 0, 0, 0);
    }
  }
#pragma unroll
  for (int s = 0; s < 8; ++s)
#pragma unroll
    for (int r = 0; r < 4; ++r)
      adj2b[(size_t)(i0 + w * 16 + q * 4 + r) * NP + k0 + s * 16 + m] = f2bf(acc[s][r]);
}

// Fused gconv phase: x1 = A@xh, x2 = A2@xh (same rhs), then epilogue.
// 1024 thr = 16 waves: wave = (k8 = wave>>1) K-slice of 640, (ns = wave&1) node half.
// EPI 1 = gate (-> xh_c, u), EPI 2 = candidate (-> h, next xh_g, projection).
template <int EPI>
__global__ __launch_bounds__(1024, 4) void k_fused(
    const unsigned short* __restrict__ adjb, const unsigned short* __restrict__ adj2b,
    const unsigned short* __restrict__ rfr, const float* __restrict__ s0F,
    const float* __restrict__ W, const float* __restrict__ bias,
    float* __restrict__ hT, float* __restrict__ uT,
    float* __restrict__ xoF, unsigned short* __restrict__ xoB,
    const float* __restrict__ inp, const float* __restrict__ Wp,
    const float* __restrict__ bp, float* __restrict__ dout,
    int mode, int tnext, int dstep) {
  constexpr int WC = (EPI == 1) ? 64 : 32;
  __shared__ float Pv[8 * 768];      // 24 KB split-K partials (one round)
  __shared__ float Ws[DN * WC];
  __shared__ float x1s[33 * 33];
  __shared__ float x2s[33 * 33];

  const int tid = threadIdx.x;
  const int wave = tid >> 6;
  const int lane = tid & 63;
  const int m = lane & 15;
  const int q = lane >> 4;
  const int ns = wave & 1;
  const int k8 = wave >> 1;
  const int nodeBase = blockIdx.x * 32;
  const int row = nodeBase + ns * 16 + m;  // A-row (zero-padded rows are valid)

  const unsigned short* aP = adjb + (size_t)row * NP + k8 * 640 + q * 8;
  const unsigned short* a2P = adj2b + (size_t)row * NP + k8 * 640 + q * 8;
  const unsigned short* xP = rfr + (size_t)(k8 * 5) * CHE + lane * 8;

  f32x4 acc[6] = {};
#pragma unroll 4
  for (int s = 0; s < 20; ++s) {
    const int koff = s * 32;
    short8 a = *(const short8*)(aP + koff);
    short8 a2 = *(const short8*)(a2P + koff);
    const unsigned short* xb = xP + (s >> 2) * CHE + (s & 3) * 512;
    short8 x0 = *(const short8*)(xb);
    short8 x1 = *(const short8*)(xb + 2048);
    short8 x2 = *(const short8*)(xb + 4096);
    acc[0] = __builtin_amdgcn_mfma_f32_16x16x32_bf16(x0, a, acc[0], 0, 0, 0);
    acc[1] = __builtin_amdgcn_mfma_f32_16x16x32_bf16(x1, a, acc[1], 0, 0, 0);
    acc[2] = __builtin_amdgcn_mfma_f32_16x16x32_bf16(x2, a, acc[2], 0, 0, 0);
    acc[3] = __builtin_amdgcn_mfma_f32_16x16x32_bf16(x0, a2, acc[3], 0, 0, 0);
    acc[4] = __builtin_amdgcn_mfma_f32_16x16x32_bf16(x1, a2, acc[4], 0, 0, 0);
    acc[5] = __builtin_amdgcn_mfma_f32_16x16x32_bf16(x2, a2, acc[5], 0, 0, 0);
  }

  // stage epilogue weights (hides under reduction barriers)
  for (int i = tid; i < DN * WC; i += 1024) Ws[i] = W[i];

  // 4 reduction rounds: (x1,ns0),(x1,ns1),(x2,ns0),(x2,ns1)
#pragma unroll 1
  for (int rd = 0; rd < 4; ++rd) {
    if ((rd & 1) == ns) {
      const int b3 = (rd & 2) ? 3 : 0;
#pragma unroll
      for (int s3 = 0; s3 < 3; ++s3)
#pragma unroll
        for (int r = 0; r < 4; ++r)
          Pv[k8 * 768 + (s3 * 16 + q * 4 + r) * 16 + m] = acc[b3 + s3][r];
    }
    __syncthreads();
    if (tid < 768) {
      int f = tid >> 4, n = tid & 15;
      if (f < FR) {
        float v = 0.f;
#pragma unroll
        for (int w8 = 0; w8 < 8; ++w8) v += Pv[w8 * 768 + tid];
        float* dst = (rd & 2) ? x2s : x1s;
        dst[f * 33 + (rd & 1) * 16 + n] = v;
      }
    }
    __syncthreads();
  }

  const int nl = tid & 31;
  const int cg = tid >> 5;  // 0..31
  const int gn = nodeBase + nl;
  const bool valid = gn < NN;
  const int gnc = valid ? gn : NN - 1;

  if constexpr (EPI == 1) {
    float a0 = bias[cg], a1 = bias[cg + 32];
    for (int f = 0; f < FR; ++f) {
      float fe = s0F[(size_t)f * NP + gnc];
      a0 += fe * Ws[f * WC + cg]; a1 += fe * Ws[f * WC + cg + 32];
    }
    for (int f = 0; f < FR; ++f) {
      float fe = x1s[f * 33 + nl];
      a0 += fe * Ws[(FR + f) * WC + cg]; a1 += fe * Ws[(FR + f) * WC + cg + 32];
    }
    for (int f = 0; f < FR; ++f) {
      float fe = x2s[f * 33 + nl];
      a0 += fe * Ws[(2 * FR + f) * WC + cg]; a1 += fe * Ws[(2 * FR + f) * WC + cg + 32];
    }
    float r = 1.f / (1.f + expf(-a0));
    float u = 1.f / (1.f + expf(-a1));
    float hv = hT[(size_t)cg * NP + gnc];
    float xc = valid ? r * hv : 0.f;
    xoF[(size_t)(1 + cg) * NP + gn] = xc;
    xoB[flatXF(1 + cg, gn)] = f2bf(xc);
    uT[(size_t)cg * NP + gn] = valid ? u : 0.f;
    if (tid < 32) {
      int g3 = nodeBase + tid;
      float v0 = s0F[g3];
      xoF[g3] = v0;
      xoB[flatXF(0, g3)] = f2bf(v0);
    }
  } else {
    float a0 = bias[cg];
    for (int f = 0; f < FR; ++f) a0 += s0F[(size_t)f * NP + gnc] * Ws[f * WC + cg];
    for (int f = 0; f < FR; ++f) a0 += x1s[f * 33 + nl] * Ws[(FR + f) * WC + cg];
    for (int f = 0; f < FR; ++f) a0 += x2s[f * 33 + nl] * Ws[(2 * FR + f) * WC + cg];
    float c = tanhf(a0);
    float u = uT[(size_t)cg * NP + gnc];
    float h0 = hT[(size_t)cg * NP + gnc];
    float hn = u * h0 + (1.f - u) * c;
    float hw = valid ? hn : 0.f;
    hT[(size_t)cg * NP + gn] = hw;
    xoF[(size_t)(1 + cg) * NP + gn] = hw;
    xoB[flatXF(1 + cg, gn)] = f2bf(hw);
    __syncthreads();               // all x1s reads done
    x1s[cg * 33 + nl] = hw;        // reuse as h scratch for projection
    __syncthreads();
    if (tid < 32) {
      int g3 = nodeBase + tid;
      bool v3 = g3 < NN;
      float x0 = 0.f;
      if (mode == 0) {
        x0 = v3 ? inp[(size_t)g3 * TT + tnext] : 0.f;
      } else if (mode == 2) {
        float p = bp[0];
        for (int j = 0; j < UU; ++j) p += x1s[j * 33 + tid] * Wp[j];
        if (v3) dout[(size_t)g3 * TT + dstep] = p;
        x0 = v3 ? p : 0.f;
      }
      xoF[g3] = x0;
      xoB[flatXF(0, g3)] = f2bf(x0);
    }
  }
}

// ---------------- fallback path (R5, proven) ----------------
constexpr int BN = 16;
constexpr int CPW = NKC / 8;
constexpr int GRID_MM = (NN + BN - 1) / BN;

__global__ void k_cast(const float* __restrict__ adj, unsigned short* __restrict__ adjb) {
  int col = (blockIdx.x * 256 + threadIdx.x) * 4;
  int row = blockIdx.y;
  float4 v = make_float4(0.f, 0.f, 0.f, 0.f);
  if (col < NN) v = *(const float4*)(adj + (size_t)row * NN + col);
  uint2 o;
  o.x = (unsigned)f2bf(v.x) | ((unsigned)f2bf(v.y) << 16);
  o.y = (unsigned)f2bf(v.z) | ((unsigned)f2bf(v.w) << 16);
  *(uint2*)(adjb + (size_t)row * NP + col) = o;
}

template <int EPI, bool USEBF>
__global__ __launch_bounds__(512, 4) void k_gemm(
    const unsigned short* __restrict__ adjb, const float* __restrict__ adjf,
    const unsigned short* __restrict__ rhs,
    float* __restrict__ outF, unsigned short* __restrict__ outB,
    const float* __restrict__ s0F, const float* __restrict__ s1F,
    const float* __restrict__ W, const float* __restrict__ bias,
    float* __restrict__ hT, float* __restrict__ uT,
    float* __restrict__ xoF, unsigned short* __restrict__ xoB,
    const float* __restrict__ inp, const float* __restrict__ Wp,
    const float* __restrict__ bp, float* __restrict__ dout,
    int mode, int tnext, int dstep) {
  constexpr int WC = (EPI == 1) ? 64 : 32;
  __shared__ float Pv[8 * FP * BN];
  __shared__ float x2s[(EPI > 0) ? FP * 17 : 1];
  __shared__ float Ws[(EPI > 0) ? DN * WC : 1];

  const int tid = threadIdx.x;
  const int wave = tid >> 6;
  const int lane = tid & 63;
  const int m = lane & 15;
  const int q = lane >> 4;
  const int nodeBase = blockIdx.x * BN;
  const int gn = nodeBase + m;
  const size_t ar = (size_t)((gn < NN) ? gn : NN - 1);

  f32x4 acc0 = {}, acc1 = {}, acc2 = {};
  short8 aCur[4], aNxt[4];

  auto loadA = [&](int i, short8* b) {
    const int k0 = (wave * CPW + i) * KC;
    if constexpr (USEBF) {
      const unsigned short* a0 = adjb + ar * NP + k0 + q * 8;
#pragma unroll
      for (int ks = 0; ks < 4; ++ks) b[ks] = *(const short8*)(a0 + ks * 32);
    } else {
      const float* a0 = adjf + ar * NN;
#pragma unroll
      for (int ks = 0; ks < 4; ++ks) {
        int kb = k0 + ks * 32 + q * 8;
        union { short8 s; unsigned short u[8]; } p0;
        if (kb + 8 <= NN) {
          float4 x0 = *(const float4*)(a0 + kb);
          float4 x1 = *(const float4*)(a0 + kb + 4);
          p0.u[0] = f2bf(x0.x); p0.u[1] = f2bf(x0.y); p0.u[2] = f2bf(x0.z); p0.u[3] = f2bf(x0.w);
          p0.u[4] = f2bf(x1.x); p0.u[5] = f2bf(x1.y); p0.u[6] = f2bf(x1.z); p0.u[7] = f2bf(x1.w);
        } else {
          for (int j = 0; j < 8; ++j) {
            int k = kb + j;
            p0.u[j] = (k < NN) ? f2bf(a0[k]) : (unsigned short)0;
          }
        }
        b[ks] = p0.s;
      }
    }
  };

  loadA(0, aCur);
#pragma unroll
  for (int i = 0; i < CPW; ++i) {
    if (i + 1 < CPW) loadA(i + 1, aNxt);
    const int ch = wave * CPW + i;
    short8 cx[12];
    const unsigned short* xb = rhs + (size_t)ch * CHE + lane * 8;
#pragma unroll
    for (int t3 = 0; t3 < 3; ++t3)
#pragma unroll
      for (int ks = 0; ks < 4; ++ks)
        cx[t3 * 4 + ks] = *(const short8*)(xb + t3 * 2048 + ks * 512);
#pragma unroll
    for (int ks = 0; ks < 4; ++ks) {
      acc0 = __builtin_amdgcn_mfma_f32_16x16x32_bf16(cx[ks], aCur[ks], acc0, 0, 0, 0);
      acc1 = __builtin_amdgcn_mfma_f32_16x16x32_bf16(cx[4 + ks], aCur[ks], acc1, 0, 0, 0);
      acc2 = __builtin_amdgcn_mfma_f32_16x16x32_bf16(cx[8 + ks], aCur[ks], acc2, 0, 0, 0);
    }
#pragma unroll
    for (int ks = 0; ks < 4; ++ks) aCur[ks] = aNxt[ks];
  }

  if constexpr (EPI > 0) {
    for (int i = tid; i < DN * WC; i += 512) Ws[i] = W[i];
  }

#pragma unroll
  for (int r = 0; r < 4; ++r) {
    Pv[wave * (FP * BN) + (q * 4 + r) * BN + m] = acc0[r];
    Pv[wave * (FP * BN) + (16 + q * 4 + r) * BN + m] = acc1[r];
    Pv[wave * (FP * BN) + (32 + q * 4 + r) * BN + m] = acc2[r];
  }
  __syncthreads();

  if constexpr (EPI == 0) {
    for (int e = tid; e < FP * BN; e += 512) {
      int f = e >> 4, n = e & 15;
      float v = 0.f;
#pragma unroll
      for (int w = 0; w < 8; ++w) v += Pv[w * (FP * BN) + e];
      int gn2 = nodeBase + n;
      if (gn2 >= NN) v = 0.f;
      outF[(size_t)f * NP + gn2] = v;
      outB[flatXF(f, gn2)] = f2bf(v);
    }
  } else {
    for (int e = tid; e < FP * BN; e += 512) {
      int f = e >> 4, n = e & 15;
      float v = 0.f;
#pragma unroll
      for (int w = 0; w < 8; ++w) v += Pv[w * (FP * BN) + e];
      x2s[f * 17 + n] = v;
    }
    __syncthreads();
    const int nl = tid & 15;
    const int cg = tid >> 4;
    const int gn2 = nodeBase + nl;
    const bool valid = gn2 < NN;
    const int gnc = valid ? gn2 : NN - 1;
    if constexpr (EPI == 1) {
      float a0 = bias[cg], a1 = bias[cg + 32];
      for (int f = 0; f < FR; ++f) {
        float fe = s0F[(size_t)f * NP + gnc];
        a0 += fe * Ws[f * WC + cg]; a1 += fe * Ws[f * WC + cg + 32];
      }
      for (int f = 0; f < FR; ++f) {
        float fe = s1F[(size_t)f * NP + gnc];
        a0 += fe * Ws[(FR + f) * WC + cg]; a1 += fe * Ws[(FR + f) * WC + cg + 32];
      }
      for (int f = 0; f < FR; ++f) {
        float fe = x2s[f * 17 + nl];
        a0 += fe * Ws[(2 * FR + f) * WC + cg]; a1 += fe * Ws[(2 * FR + f) * WC + cg + 32];
      }
      float r = 1.f / (1.f + expf(-a0));
      float hv = hT[(size_t)cg * NP + gnc];
      float xc = valid ? r * hv : 0.f;
      xoF[(size_t)(1 + cg) * NP + gn2] = xc;
      xoB[flatXF(1 + cg, gn2)] = f2bf(xc);
      float u = 1.f / (1.f + expf(-a1));
      uT[(size_t)cg * NP + gn2] = valid ? u : 0.f;
      if (tid < BN) {
        int g3 = nodeBase + tid;
        float v0 = s0F[g3];
        xoF[g3] = v0;
        xoB[flatXF(0, g3)] = f2bf(v0);
      }
    } else {
      float a0 = bias[cg];
      for (int f = 0; f < FR; ++f) a0 += s0F[(size_t)f * NP + gnc] * Ws[f * WC + cg];
      for (int f = 0; f < FR; ++f) a0 += s1F[(size_t)f * NP + gnc] * Ws[(FR + f) * WC + cg];
      for (int f = 0; f < FR; ++f) a0 += x2s[f * 17 + nl] * Ws[(2 * FR + f) * WC + cg];
      float c = tanhf(a0);
      float u = uT[(size_t)cg * NP + gnc];
      float h0 = hT[(size_t)cg * NP + gnc];
      float hn = u * h0 + (1.f - u) * c;
      float hw = valid ? hn : 0.f;
      hT[(size_t)cg * NP + gn2] = hw;
      xoF[(size_t)(1 + cg) * NP + gn2] = hw;
      xoB[flatXF(1 + cg, gn2)] = f2bf(hw);
      __syncthreads();
      x2s[cg * 17 + nl] = hw;
      __syncthreads();
      if (tid < BN) {
        int g3 = nodeBase + tid;
        bool v3 = g3 < NN;
        float x0 = 0.f;
        if (mode == 0) {
          x0 = v3 ? inp[(size_t)g3 * TT + tnext] : 0.f;
        } else if (mode == 2) {
          float p = bp[0];
          for (int j = 0; j < UU; ++j) p += x2s[j * 17 + tid] * Wp[j];
          if (v3) dout[(size_t)g3 * TT + dstep] = p;
          x0 = v3 ? p : 0.f;
        }
        xoF[g3] = x0;
        xoB[flatXF(0, g3)] = f2bf(x0);
      }
    }
  }
}

extern "C" void kernel_launch(void* const* d_in, const int* in_sizes, int n_in,
                              void* d_out, int out_size, void* d_ws, size_t ws_size,
                              hipStream_t stream) {
  const float* inputs = (const float*)d_in[0];
  const float* adj = (const float*)d_in[2];
  const float* eWg = (const float*)d_in[3];
  const float* eBg = (const float*)d_in[4];
  const float* eWc = (const float*)d_in[5];
  const float* eBc = (const float*)d_in[6];
  const float* dWg = (const float*)d_in[7];
  const float* dBg = (const float*)d_in[8];
  const float* dWc = (const float*)d_in[9];
  const float* dBc = (const float*)d_in[10];
  const float* Wp = (const float*)d_in[11];
  const float* bp = (const float*)d_in[12];
  float* dout = (float*)d_out;
  char* ws = (char*)d_ws;

  // ---- fused-path workspace ----
  size_t o = 0;
  unsigned short* adjb = (unsigned short*)(ws + o); o += (size_t)NP * NP * 2;
  unsigned short* adjT = (unsigned short*)(ws + o); o += (size_t)NP * NP * 2;
  unsigned short* adj2b = (unsigned short*)(ws + o); o += (size_t)NP * NP * 2;
  size_t zbase = o;
  unsigned short* xhGfr = (unsigned short*)(ws + o); o += (size_t)NKC * CHE * 2;
  unsigned short* xhCfr = (unsigned short*)(ws + o); o += (size_t)NKC * CHE * 2;
  float* xhGf = (float*)(ws + o); o += (size_t)FR * NP * 4;
  float* xhCf = (float*)(ws + o); o += (size_t)FR * NP * 4;
  float* hT = (float*)(ws + o); o += (size_t)UU * NP * 4;
  float* uT = (float*)(ws + o); o += (size_t)UU * NP * 4;
  size_t need_fused = o;

  if (ws_size >= need_fused) {
    size_t zbytes = need_fused - zbase;
    k_zero<<<(int)((zbytes / 16 + 255) / 256), 256, 0, stream>>>(
        (uint4*)(ws + zbase), (int)(zbytes / 16));
    k_castT<<<dim3(NP / 64, NP / 64), 256, 0, stream>>>(adj, adjb, adjT);
    k_sq<<<dim3(NP / 128, NP / 128), 512, 0, stream>>>(adjb, adjT, adj2b);
    k_initx0<<<NP / 256, 256, 0, stream>>>(inputs, xhGf, xhGfr);

    const int GF = (NN + 31) / 32;  // 157
    for (int t = 0; t < 2 * TT; ++t) {
      bool enc = t < TT;
      const float* Wg = enc ? eWg : dWg;
      const float* Bg = enc ? eBg : dBg;
      const float* Wc = enc ? eWc : dWc;
      const float* Bc = enc ? eBc : dBc;
      int mode, tn = 0, ds = 0;
      if (t < TT - 1) { mode = 0; tn = t + 1; }
      else if (t == TT - 1) { mode = 1; }
      else { mode = 2; ds = t - TT; }

      k_fused<1><<<GF, 1024, 0, stream>>>(
          adjb, adj2b, xhGfr, xhGf, Wg, Bg, hT, uT, xhCf, xhCfr,
          nullptr, nullptr, nullptr, nullptr, 0, 0, 0);
      k_fused<2><<<GF, 1024, 0, stream>>>(
          adjb, adj2b, xhCfr, xhCf, Wc, Bc, hT, uT, xhGf, xhGfr,
          inputs, Wp, bp, dout, mode, tn, ds);
    }
    return;
  }

  // ---- fallback: R5 proven path ----
  o = 0;
  float* fxhGf = (float*)(ws + o); o += (size_t)FP * NP * 4;
  unsigned short* fxhGb = (unsigned short*)(ws + o); o += (size_t)FP * NP * 2;
  float* fxhCf = (float*)(ws + o); o += (size_t)FP * NP * 4;
  unsigned short* fxhCb = (unsigned short*)(ws + o); o += (size_t)FP * NP * 2;
  float* fx1f = (float*)(ws + o); o += (size_t)FP * NP * 4;
  unsigned short* fx1b = (unsigned short*)(ws + o); o += (size_t)FP * NP * 2;
  float* fhT = (float*)(ws + o); o += (size_t)UU * NP * 4;
  float* fuT = (float*)(ws + o); o += (size_t)UU * NP * 4;
  size_t small = o;
  unsigned short* fadjb = (unsigned short*)(ws + o);
  size_t need = o + (size_t)NN * NP * 2;
  bool usebf = ws_size >= need;

  k_zero<<<(int)((small / 16 + 255) / 256), 256, 0, stream>>>((uint4*)ws, (int)(small / 16));
  if (usebf) k_cast<<<dim3(5, NN), 256, 0, stream>>>(adj, fadjb);
  k_initx0<<<NP / 256, 256, 0, stream>>>(inputs, fxhGf, fxhGb);

  auto run = [&](auto ubc) {
    constexpr bool UB = decltype(ubc)::value;
    const unsigned short* ab = UB ? fadjb : nullptr;
    for (int t = 0; t < 2 * TT; ++t) {
      bool enc = t < TT;
      const float* Wg = enc ? eWg : dWg;
      const float* Bg = enc ? eBg : dBg;
      const float* Wc = enc ? eWc : dWc;
      const float* Bc = enc ? eBc : dBc;
      int mode, tn = 0, ds = 0;
      if (t < TT - 1) { mode = 0; tn = t + 1; }
      else if (t == TT - 1) { mode = 1; }
      else { mode = 2; ds = t - TT; }

      k_gemm<0, UB><<<GRID_MM, 512, 0, stream>>>(
          ab, adj, fxhGb, fx1f, fx1b,
          nullptr, nullptr, nullptr, nullptr, nullptr, nullptr,
          nullptr, nullptr, nullptr, nullptr, nullptr, nullptr, 0, 0, 0);
      k_gemm<1, UB><<<GRID_MM, 512, 0, stream>>>(
          ab, adj, fx1b, nullptr, nullptr,
          fxhGf, fx1f, Wg, Bg, fhT, fuT, fxhCf, fxhCb,
          nullptr, nullptr, nullptr, nullptr, 0, 0, 0);
      k_gemm<0, UB><<<GRID_MM, 512, 0, stream>>>(
          ab, adj, fxhCb, fx1f, fx1b,
          nullptr, nullptr, nullptr, nullptr, nullptr, nullptr,
          nullptr, nullptr, nullptr, nullptr, nullptr, nullptr, 0, 0, 0);
      k_gemm<2, UB><<<GRID_MM, 512, 0, stream>>>(
          ab, adj, fx1b, nullptr, nullptr,
          fxhCf, fx1f, Wc, Bc, fhT, fuT, fxhGf, fxhGb,
          inputs, Wp, bp, dout, mode, tn, ds);
    }
  };
  if (usebf) run(std::integral_constant<bool, true>{});
  else run(std::integral_constant<bool, false>{});
}